// Round 18
// baseline (2394.876 us; speedup 1.0000x reference)
//
#include <hip/hip_runtime.h>
#include <hip/hip_bf16.h>
#include <hip/hip_fp16.h>

// GPT-2 small forward (B=2,S=1024,L=12,D=768,H=12,V=50257) on gfx950.
// Round 18 = r17 + counted-vmcnt double-buffered K-loop on the TM=64/TN=64
// GEMM path (all 48 layer GEMMs): issue tile t+1's 8 loads -> s_waitcnt
// vmcnt(8) (tile t retired, t+1 in flight) -> raw s_barrier -> compute ->
// raw s_barrier. This is T4 (m218: counted-vs-drain0 +38-73%) — the piece
// r4's dbuf lacked (its __syncthreads drained vmcnt to 0). LM head keeps
// the verified r9 structure. LDS 32KB -> still 5 blocks/CU at 128 thr.

typedef __attribute__((ext_vector_type(8))) short short8;
typedef __attribute__((ext_vector_type(4))) float f32x4;

#define S_LEN  1024
#define NTOK   2048
#define DMODEL 768
#define NHEAD  12
#define HEADD  64
#define NLAYER 12
#define VOCAB  50257
#define DQKV   2304
#define DFF    3072

__device__ __forceinline__ unsigned short f2bf(float f) {
  unsigned u = __float_as_uint(f);
  u += 0x7fffu + ((u >> 16) & 1u);
  return (unsigned short)(u >> 16);
}
__device__ __forceinline__ unsigned short f2h(float f) {
  __half h = __float2half(f);
  return *reinterpret_cast<unsigned short*>(&h);
}

__device__ __forceinline__ f32x4 mfma_bf16(short8 a, short8 b, f32x4 c) {
  asm("v_mfma_f32_16x16x32_bf16 %0, %1, %2, %0" : "+v"(c) : "v"(a), "v"(b));
  return c;
}
__device__ __forceinline__ f32x4 mfma_f16(short8 a, short8 b, f32x4 c) {
  asm("v_mfma_f32_16x16x32_f16 %0, %1, %2, %0" : "+v"(c) : "v"(a), "v"(b));
  return c;
}

// async global->LDS, 16 bytes per lane (dest = wave-uniform base + lane*16)
__device__ __forceinline__ void gll16(const void* g, void* l) {
  __builtin_amdgcn_global_load_lds(
      (const __attribute__((address_space(1))) void*)g,
      (__attribute__((address_space(3))) void*)l, 16, 0, 0);
}

// ---------------- embedding ----------------
__global__ __launch_bounds__(256) void embed_kernel(
    const int* __restrict__ ids, const float* __restrict__ wte,
    const float* __restrict__ wpe, float* __restrict__ x) {
  int i = blockIdx.x * 256 + threadIdx.x;
  int n = i / DMODEL, d = i - n * DMODEL;
  int s = n & (S_LEN - 1);
  x[i] = wte[(long)ids[n] * DMODEL + d] + wpe[(long)s * DMODEL + d];
}

// ---------------- f32 -> bf16 convert (x4) ----------------
__global__ __launch_bounds__(256) void convert_kernel(
    const float* __restrict__ in, unsigned short* __restrict__ out, long n4) {
  long i = (long)blockIdx.x * 256 + threadIdx.x;
  if (i >= n4) return;
  float4 v = ((const float4*)in)[i];
  ushort4 r;
  r.x = f2bf(v.x); r.y = f2bf(v.y); r.z = f2bf(v.z); r.w = f2bf(v.w);
  ((ushort4*)out)[i] = r;
}

// ---------------- transpose f32[R][C] -> bf16[C][R], batched over z ----------------
__global__ __launch_bounds__(256) void transpose_kernel(
    const float* __restrict__ in, unsigned short* __restrict__ out, int R, int C,
    long ldin, long ldout) {
  in  += (long)blockIdx.z * ldin;
  out += (long)blockIdx.z * ldout;
  __shared__ float tile[32][33];
  int tx = threadIdx.x & 31, ty = threadIdx.x >> 5;
  int c0 = blockIdx.x * 32, r0 = blockIdx.y * 32;
#pragma unroll
  for (int i = 0; i < 4; ++i) {
    int r = r0 + ty + i * 8;
    tile[ty + i * 8][tx] = in[(long)r * C + c0 + tx];
  }
  __syncthreads();
#pragma unroll
  for (int i = 0; i < 4; ++i) {
    int orow = c0 + ty + i * 8;
    out[(long)orow * R + r0 + tx] = f2bf(tile[tx][ty + i * 8]);
  }
}

// ---------------- layernorm: f32 in -> bf16 out ----------------
__global__ __launch_bounds__(256) void ln_kernel(
    const float* __restrict__ x, const float* __restrict__ g,
    const float* __restrict__ b, unsigned short* __restrict__ out) {
  __shared__ float sb[4];
  int n = blockIdx.x, t = threadIdx.x;
  const float* xr = x + (long)n * DMODEL;
  float v0 = xr[t], v1 = xr[t + 256], v2 = xr[t + 512];
  float sum = v0 + v1 + v2;
#pragma unroll
  for (int o = 32; o; o >>= 1) sum += __shfl_xor(sum, o);
  if ((t & 63) == 0) sb[t >> 6] = sum;
  __syncthreads();
  sum = sb[0] + sb[1] + sb[2] + sb[3];
  float mean = sum * (1.f / 768.f);
  float d0 = v0 - mean, d1 = v1 - mean, d2 = v2 - mean;
  float vs = d0 * d0 + d1 * d1 + d2 * d2;
#pragma unroll
  for (int o = 32; o; o >>= 1) vs += __shfl_xor(vs, o);
  __syncthreads();
  if ((t & 63) == 0) sb[t >> 6] = vs;
  __syncthreads();
  vs = sb[0] + sb[1] + sb[2] + sb[3];
  float rs = rsqrtf(vs * (1.f / 768.f) + 1e-5f);
  out[(long)n * DMODEL + t]       = f2bf(d0 * rs * g[t] + b[t]);
  out[(long)n * DMODEL + t + 256] = f2bf(d1 * rs * g[t + 256] + b[t + 256]);
  out[(long)n * DMODEL + t + 512] = f2bf(d2 * rs * g[t + 512] + b[t + 512]);
}

// ---------------- MFMA flash attention (all-f16 QKV, r9-verified) ----------------
// qkv: f16 [NTOK][2304]. o: bf16 [NTOK][768].
// grid = (S/64, B*H), block 256 = 4 waves; wave w owns q-rows w*16..w*16+15.
__global__ __launch_bounds__(256) void attn_kernel(
    const unsigned short* __restrict__ qkv, unsigned short* __restrict__ o_out) {
  __shared__ __align__(16) unsigned short Ks[64 * 64];  // K (f16), XOR-swizzled rows
  __shared__ __align__(16) unsigned short Vt[64 * 64];  // [dv][key] f16, swizzled
  __shared__ __align__(16) unsigned short Ps[4][16 * 72];
  int t = threadIdx.x, w = t >> 6, l = t & 63;
  int qtile = gridDim.x - 1 - blockIdx.x;   // heavy-first
  int bh = blockIdx.y;
  int b = bh / NHEAD, h = bh - b * NHEAD;
  long nb = (long)b * S_LEN;
  int g = l >> 4, lr = l & 15;

  int q0 = qtile * 64 + w * 16;
  const unsigned short* qrow = qkv + (nb + q0 + lr) * (long)DQKV + h * HEADD;
  short8 qf0 = *(const short8*)(qrow + g * 8);
  short8 qf1 = *(const short8*)(qrow + 32 + g * 8);

  f32x4 O[4];
  f32x4 zero = {0.f, 0.f, 0.f, 0.f};
#pragma unroll
  for (int jt = 0; jt < 4; ++jt) O[jt] = zero;
  float m[4] = {-INFINITY, -INFINITY, -INFINITY, -INFINITY};
  float ls[4] = {0.f, 0.f, 0.f, 0.f};

  int skey = t >> 2;            // V staging: key row
  int sd0 = (t & 3) * 16;       // V staging: dv0
  int nt = qtile + 1;
  for (int c = 0; c < nt; ++c) {
    int k0 = c * 64;
    __syncthreads();
    // ---- stage K (f16) via global_load_lds, source pre-swizzled ----
    {
      int c0 = t, row = c0 >> 3, j = c0 & 7;
      long goff = (nb + k0 + row) * (long)DQKV + DMODEL + h * HEADD + ((j ^ (row & 7)) * 8);
      gll16(qkv + goff, (char*)Ks + c0 * 16);
      int c1 = t + 256; row = c1 >> 3; j = c1 & 7;
      goff = (nb + k0 + row) * (long)DQKV + DMODEL + h * HEADD + ((j ^ (row & 7)) * 8);
      gll16(qkv + goff, (char*)Ks + c1 * 16);
    }
    // ---- stage V transposed (reg-staged, swizzled 2B writes, f16 passthrough) ----
    {
      const unsigned short* vr =
          qkv + (nb + k0 + skey) * (long)DQKV + 2 * DMODEL + h * HEADD + sd0;
      short8 v0 = *(const short8*)vr;
      short8 v1 = *(const short8*)(vr + 8);
#pragma unroll
      for (int j = 0; j < 8; ++j) {
        int dv = sd0 + j;
        *(unsigned short*)((char*)Vt + dv * 128 + ((skey * 2) ^ ((dv & 7) << 4))) =
            (unsigned short)v0[j];
        dv = sd0 + 8 + j;
        *(unsigned short*)((char*)Vt + dv * 128 + ((skey * 2) ^ ((dv & 7) << 4))) =
            (unsigned short)v1[j];
      }
    }
    __syncthreads();

    // ---- S = Q K^T (f16 inputs, f32 accum) — T5: setprio around MFMA ----
    f32x4 S[4];
    __builtin_amdgcn_s_setprio(1);
#pragma unroll
    for (int kt = 0; kt < 4; ++kt) {
      int krow = kt * 16 + lr;
      int o0 = (g * 16) ^ ((krow & 7) << 4);
      int o1 = (64 + g * 16) ^ ((krow & 7) << 4);
      short8 kf0 = *(const short8*)((char*)Ks + krow * 128 + o0);
      short8 kf1 = *(const short8*)((char*)Ks + krow * 128 + o1);
      S[kt] = mfma_f16(qf0, kf0, zero);
      S[kt] = mfma_f16(qf1, kf1, S[kt]);
    }
    __builtin_amdgcn_s_setprio(0);

    // ---- mask + online softmax (rows lane-local: q = g*4+r) ----
    bool diag = (c == qtile);
    float sv[4][4];
#pragma unroll
    for (int kt = 0; kt < 4; ++kt)
#pragma unroll
      for (int r = 0; r < 4; ++r) {
        float xv = S[kt][r] * 0.125f;
        if (diag) {
          int key = kt * 16 + lr;
          int qq = w * 16 + g * 4 + r;
          if (key > qq) xv = -INFINITY;
        }
        sv[kt][r] = xv;
      }
    float nm[4], al[4];
#pragma unroll
    for (int r = 0; r < 4; ++r) {
      float mx = fmaxf(fmaxf(sv[0][r], sv[1][r]), fmaxf(sv[2][r], sv[3][r]));
#pragma unroll
      for (int o = 8; o; o >>= 1) mx = fmaxf(mx, __shfl_xor(mx, o));
      nm[r] = fmaxf(m[r], mx);
      al[r] = __expf(m[r] - nm[r]);
      m[r] = nm[r];
    }
    float rs[4] = {0.f, 0.f, 0.f, 0.f};
#pragma unroll
    for (int kt = 0; kt < 4; ++kt)
#pragma unroll
      for (int r = 0; r < 4; ++r) {
        float p = __expf(sv[kt][r] - nm[r]);
        rs[r] += p;
        Ps[w][(g * 4 + r) * 72 + kt * 16 + lr] = f2h(p);
      }
#pragma unroll
    for (int r = 0; r < 4; ++r) {
#pragma unroll
      for (int o = 8; o; o >>= 1) rs[r] += __shfl_xor(rs[r], o);
      ls[r] = ls[r] * al[r] + rs[r];
    }
#pragma unroll
    for (int jt = 0; jt < 4; ++jt) {
      f32x4 ov = O[jt];
#pragma unroll
      for (int r = 0; r < 4; ++r) ov[r] *= al[r];
      O[jt] = ov;
    }
    // ---- O += P V (f16) — T5: setprio around MFMA ----
    __builtin_amdgcn_s_setprio(1);
#pragma unroll
    for (int kk = 0; kk < 2; ++kk) {
      short8 pf = *(const short8*)(&Ps[w][lr * 72 + kk * 32 + g * 8]);
#pragma unroll
      for (int jt = 0; jt < 4; ++jt) {
        int dv = jt * 16 + lr;
        short8 vf = *(const short8*)((char*)Vt + dv * 128 +
                                     (((kk * 64 + g * 16)) ^ ((dv & 7) << 4)));
        O[jt] = mfma_f16(pf, vf, O[jt]);
      }
    }
    __builtin_amdgcn_s_setprio(0);
  }

  // ---- epilogue: normalize, stage in Ks, coalesced store (bf16 out) ----
  __syncthreads();
#pragma unroll
  for (int jt = 0; jt < 4; ++jt)
#pragma unroll
    for (int r = 0; r < 4; ++r) {
      int qq = w * 16 + g * 4 + r;
      int dv = jt * 16 + lr;
      *(unsigned short*)((char*)Ks + qq * 128 + ((dv * 2) ^ ((qq & 7) << 4))) =
          f2bf(O[jt][r] / ls[r]);
    }
  __syncthreads();
  {
    int qq = t >> 2, d0 = (t & 3) * 16;
    short8 o0 = *(const short8*)((char*)Ks + qq * 128 + ((d0 * 2) ^ ((qq & 7) << 4)));
    short8 o1 = *(const short8*)((char*)Ks + qq * 128 + (((d0 + 8) * 2) ^ ((qq & 7) << 4)));
    unsigned short* orow = o_out + (nb + qtile * 64 + qq) * (long)DMODEL + h * HEADD + d0;
    *(short8*)orow = o0;
    *(short8*)(orow + 8) = o1;
  }
}

// ---------------- bf16 MFMA GEMM, B^T layout, global_load_lds staging ----------------
// C[M][Nv] = act(A[M][K] * Bt[Nv][K]^T + bias).  K%64==0.
// TM=64/TN=64: counted-vmcnt double-buffered K-tiles (T4); 2 waves, 128 thr.
// TM=128 (TN=128): verified r9 2-subtile drain loop; 4 waves, 256 thr.
template <int TM, int TN, int HAS_BIAS, int ACT_GELU, int RESID, int OUT_BF16,
          int OUT_F16, int COLG, int GRIDSWAP, int XCDSWZ>
__global__ __launch_bounds__(TM == 128 ? 256 : 128) void gemm_bt_kernel(
    const short* __restrict__ A, const short* __restrict__ Bt,
    const float* __restrict__ bias, float* __restrict__ Cf,
    unsigned short* __restrict__ Cb, int K, int Nv) {
  constexpr int NB = (TM == 64 && TN == 64) ? 2 : 1;   // K-tile double buffer
  __shared__ __align__(16) short As[NB * 2][TM * 32];
  __shared__ __align__(16) short Bs[NB * 2][TN * 32];
  constexpr int NJ = (TN == 64) ? 2 : 4;        // N-frags per wave
  constexpr int WN = (TN == 64) ? 32 : 64;      // wave N-stride
  int t = threadIdx.x;
  int lane = t & 63, wave = t >> 6;
  int wm = (TM == 128) ? (wave >> 1) : 0;
  int wn = (TM == 128) ? (wave & 1) : wave;

  int bx = blockIdx.x, by = blockIdx.y;
  if (XCDSWZ) {
    int gx = gridDim.x;
    int nwg = gx * gridDim.y;
    int wg = by * gx + bx;
    int q8 = nwg >> 3, r8 = nwg & 7;
    int xcd = wg & 7, idx = wg >> 3;
    int nid = (xcd < r8 ? xcd * (q8 + 1) : r8 * (q8 + 1) + (xcd - r8) * q8) + idx;
    bx = nid % gx;
    by = nid / gx;
  }
  int row0 = (GRIDSWAP ? bx : by) * TM;
  int col0 = (GRIDSWAP ? by : bx) * TN;
  int lr = lane & 15, lk = (lane >> 4) * 8;

  f32x4 acc[4][NJ];
  f32x4 zero = {0.f, 0.f, 0.f, 0.f};
#pragma unroll
  for (int i = 0; i < 4; ++i)
#pragma unroll
    for (int j = 0; j < NJ; ++j) acc[i][j] = zero;

  int rr = t >> 2, k8 = (t & 3) * 8;

  if (TM == 128) {
    int ar0 = row0 + rr, ar1 = ar0 + 64;
    int br0 = col0 + rr, br1 = br0 + 64;
    if (COLG) { br0 = min(br0, Nv - 1); br1 = min(br1, Nv - 1); }
    const short* Ap0 = A + (long)ar0 * K + k8;
    const short* Ap1 = A + (long)ar1 * K + k8;
    const short* Bp0 = Bt + (long)br0 * K + k8;
    const short* Bp1 = Bt + (long)br1 * K + k8;
    for (int kt = 0; kt < K; kt += 64) {
      __syncthreads();
#pragma unroll
      for (int s = 0; s < 2; ++s) {
        int ko = kt + s * 32;
        gll16(Ap0 + ko, (char*)As[s] + t * 16);
        gll16(Ap1 + ko, (char*)As[s] + 4096 + t * 16);
        gll16(Bp0 + ko, (char*)Bs[s] + t * 16);
        gll16(Bp1 + ko, (char*)Bs[s] + 4096 + t * 16);
      }
      __syncthreads();
#pragma unroll
      for (int s = 0; s < 2; ++s) {
        short8 af[4], bfr[4];
#pragma unroll
        for (int i = 0; i < 4; ++i) {
          af[i]  = *(const short8*)(As[s] + (wm * 64 + i * 16 + lr) * 32 + lk);
          bfr[i] = *(const short8*)(Bs[s] + (wn * 64 + i * 16 + lr) * 32 + lk);
        }
#pragma unroll
        for (int i = 0; i < 4; ++i)
#pragma unroll
          for (int j = 0; j < 4; ++j)
            acc[i][j] = mfma_bf16(af[i], bfr[j], acc[i][j]);
      }
    }
  } else if (TN == 128) {
    // TM == 64, TN == 128, 128 threads (unused path; r9 structure)
    const short* Ap = A + (long)(row0 + rr) * K + k8;
    const short* Bp = Bt + (long)(col0 + rr) * K + k8;
    for (int kt = 0; kt < K; kt += 64) {
      __syncthreads();
#pragma unroll
      for (int s = 0; s < 2; ++s) {
        int ko = kt + s * 32;
        gll16(Ap + ko, (char*)As[s] + t * 16);
        gll16(Ap + (long)32 * K + ko, (char*)As[s] + 2048 + t * 16);
        gll16(Bp + ko, (char*)Bs[s] + t * 16);
        gll16(Bp + (long)32 * K + ko, (char*)Bs[s] + 2048 + t * 16);
        gll16(Bp + (long)64 * K + ko, (char*)Bs[s] + 4096 + t * 16);
        gll16(Bp + (long)96 * K + ko, (char*)Bs[s] + 6144 + t * 16);
      }
      __syncthreads();
#pragma unroll
      for (int s = 0; s < 2; ++s) {
        short8 af[4], bfr[4];
#pragma unroll
        for (int i = 0; i < 4; ++i) {
          af[i]  = *(const short8*)(As[s] + (i * 16 + lr) * 32 + lk);
          bfr[i] = *(const short8*)(Bs[s] + (wn * 64 + i * 16 + lr) * 32 + lk);
        }
#pragma unroll
        for (int i = 0; i < 4; ++i)
#pragma unroll
          for (int j = 0; j < 4; ++j)
            acc[i][j] = mfma_bf16(af[i], bfr[j], acc[i][j]);
      }
    }
  } else {
    // TM == 64, TN == 64, 128 threads: counted-vmcnt double-buffered K-tiles.
    // Per K-tile: 8 gll16. Steady state: issue 8 for buf[cur^1], then
    // s_waitcnt vmcnt(8) -> only buf[cur]'s 8 retired; raw barrier; compute;
    // raw barrier (all waves done reading buf[cur] before next overwrite).
    const short* Ap = A + (long)(row0 + rr) * K + k8;
    const short* Bp = Bt + (long)(col0 + rr) * K + k8;
    auto issue8 = [&](int bsel, int kb) {
#pragma unroll
      for (int s = 0; s < 2; ++s) {
        int ko = kb + s * 32;
        gll16(Ap + ko, (char*)As[bsel * 2 + s] + t * 16);
        gll16(Ap + (long)32 * K + ko, (char*)As[bsel * 2 + s] + 2048 + t * 16);
        gll16(Bp + ko, (char*)Bs[bsel * 2 + s] + t * 16);
        gll16(Bp + (long)32 * K + ko, (char*)Bs[bsel * 2 + s] + 2048 + t * 16);
      }
    };
    issue8(0, 0);
    int cur = 0;
    for (int kt = 0; kt < K; kt += 64) {
      if (kt + 64 < K) {
        issue8(cur ^ 1, kt + 64);
        asm volatile("s_waitcnt vmcnt(8)" ::: "memory");
      } else {
        asm volatile("s_waitcnt vmcnt(0)" ::: "memory");
      }
      __builtin_amdgcn_sched_barrier(0);
      __builtin_amdgcn_s_barrier();          // buf[cur] fully staged (all waves)
#pragma unroll
      for (int s = 0; s < 2; ++s) {
        short8 af[4], bfr[2];
#pragma unroll
        for (int i = 0; i < 4; ++i)
          af[i] = *(const short8*)(As[cur * 2 + s] + (i * 16 + lr) * 32 + lk);
#pragma unroll
        for (int j = 0; j < 2; ++j)
          bfr[j] = *(const short8*)(Bs[cur * 2 + s] + (wn * 32 + j * 16 + lr) * 32 + lk);
#pragma unroll
        for (int i = 0; i < 4; ++i)
#pragma unroll
          for (int j = 0; j < 2; ++j)
            acc[i][j] = mfma_bf16(af[i], bfr[j], acc[i][j]);
      }
      __builtin_amdgcn_s_barrier();          // reads done before buf reuse
      cur ^= 1;
    }
  }

  int orow = row0 + wm * 64 + (lane >> 4) * 4;
  int ocol = col0 + wn * WN + lr;
#pragma unroll
  for (int i = 0; i < 4; ++i) {
#pragma unroll
    for (int j = 0; j < NJ; ++j) {
      int col = ocol + j * 16;
      if (COLG && col >= Nv) continue;
      float bv = 0.f;
      if (HAS_BIAS) bv = bias[col];
#pragma unroll
      for (int r = 0; r < 4; ++r) {
        float xv = acc[i][j][r] + bv;
        if (ACT_GELU) xv = 0.5f * xv * (1.f + erff(xv * 0.70710678118654752f));
        long idx = (long)(orow + i * 16 + r) * Nv + col;
        if (RESID) {
          Cf[idx] += xv;
        } else if (OUT_F16) {
          Cb[idx] = f2h(xv);
        } else if (OUT_BF16) {
          Cb[idx] = f2bf(xv);
        } else {
          Cf[idx] = xv;
        }
      }
    }
  }
}

extern "C" void kernel_launch(void* const* d_in, const int* in_sizes, int n_in,
                              void* d_out, int out_size, void* d_ws, size_t ws_size,
                              hipStream_t stream) {
  const int*   ids  = (const int*)d_in[0];
  const float* wte  = (const float*)d_in[1];
  const float* wpe  = (const float*)d_in[2];
  const float* ln1g = (const float*)d_in[3];
  const float* ln1b = (const float*)d_in[4];
  const float* Wqkv = (const float*)d_in[5];
  const float* bqkv = (const float*)d_in[6];
  const float* Wo   = (const float*)d_in[7];
  const float* bo   = (const float*)d_in[8];
  const float* ln2g = (const float*)d_in[9];
  const float* ln2b = (const float*)d_in[10];
  const float* Wfc  = (const float*)d_in[11];
  const float* bfc  = (const float*)d_in[12];
  const float* Wp   = (const float*)d_in[13];
  const float* bp   = (const float*)d_in[14];
  const float* lnfg = (const float*)d_in[15];
  const float* lnfb = (const float*)d_in[16];
  float* out = (float*)d_out;

  size_t off = 0;
  auto carve = [&](size_t bytes) {
    void* p = (char*)d_ws + off;
    off += (bytes + 255) & ~(size_t)255;
    return p;
  };
  float* x = (float*)carve((size_t)NTOK * DMODEL * 4);
  unsigned short* qkvb = (unsigned short*)carve((size_t)NTOK * DQKV * 2);
  unsigned short* h    = (unsigned short*)carve((size_t)NTOK * DMODEL * 2);
  unsigned short* ob   = (unsigned short*)carve((size_t)NTOK * DMODEL * 2);
  unsigned short* mb   = (unsigned short*)carve((size_t)NTOK * DFF * 2);
  unsigned short* wteb = (unsigned short*)carve((size_t)VOCAB * DMODEL * 2);

  const size_t szQ = (size_t)DMODEL * DQKV * 2, szO = (size_t)DMODEL * DMODEL * 2;
  const size_t szF = (size_t)DMODEL * DFF * 2,  szP = (size_t)DFF * DMODEL * 2;
  size_t fixed_end = off;
  size_t full_need = fixed_end + NLAYER * (szQ + szO + szF + szP) + 4 * 256;
  bool full = ws_size >= full_need;

  unsigned short *tQ, *tO, *tF, *tP;
  if (full) {
    tQ = (unsigned short*)carve(NLAYER * szQ);
    tO = (unsigned short*)carve(NLAYER * szO);
    tF = (unsigned short*)carve(NLAYER * szF);
    tP = (unsigned short*)carve(NLAYER * szP);
  } else {
    tQ = (unsigned short*)carve(szQ);
    tO = (unsigned short*)carve(szO);
    tF = (unsigned short*)carve(szF);
    tP = (unsigned short*)carve(szP);
  }
  if (off > ws_size) return;

  dim3 blk(256), blk128(128);
  long n4 = (long)VOCAB * DMODEL / 4;
  convert_kernel<<<dim3((unsigned)((n4 + 255) / 256)), blk, 0, stream>>>(wte, wteb, n4);
  embed_kernel<<<dim3(NTOK * DMODEL / 256), blk, 0, stream>>>(ids, wte, wpe, x);

  if (full) {
    transpose_kernel<<<dim3(DQKV / 32, DMODEL / 32, NLAYER), blk, 0, stream>>>(
        Wqkv, tQ, DMODEL, DQKV, (long)DMODEL * DQKV, (long)DMODEL * DQKV);
    transpose_kernel<<<dim3(DMODEL / 32, DMODEL / 32, NLAYER), blk, 0, stream>>>(
        Wo, tO, DMODEL, DMODEL, (long)DMODEL * DMODEL, (long)DMODEL * DMODEL);
    transpose_kernel<<<dim3(DFF / 32, DMODEL / 32, NLAYER), blk, 0, stream>>>(
        Wfc, tF, DMODEL, DFF, (long)DMODEL * DFF, (long)DMODEL * DFF);
    transpose_kernel<<<dim3(DMODEL / 32, DFF / 32, NLAYER), blk, 0, stream>>>(
        Wp, tP, DFF, DMODEL, (long)DFF * DMODEL, (long)DFF * DMODEL);
  }

  for (int l = 0; l < NLAYER; ++l) {
    const unsigned short* tQl = tQ + (full ? (size_t)l * DMODEL * DQKV : 0);
    const unsigned short* tOl = tO + (full ? (size_t)l * DMODEL * DMODEL : 0);
    const unsigned short* tFl = tF + (full ? (size_t)l * DMODEL * DFF : 0);
    const unsigned short* tPl = tP + (full ? (size_t)l * DFF * DMODEL : 0);
    if (!full) {
      transpose_kernel<<<dim3(DQKV / 32, DMODEL / 32), blk, 0, stream>>>(
          Wqkv + (long)l * DMODEL * DQKV, tQ, DMODEL, DQKV, 0, 0);
      transpose_kernel<<<dim3(DMODEL / 32, DMODEL / 32), blk, 0, stream>>>(
          Wo + (long)l * DMODEL * DMODEL, tO, DMODEL, DMODEL, 0, 0);
      transpose_kernel<<<dim3(DFF / 32, DMODEL / 32), blk, 0, stream>>>(
          Wfc + (long)l * DMODEL * DFF, tF, DMODEL, DFF, 0, 0);
      transpose_kernel<<<dim3(DMODEL / 32, DFF / 32), blk, 0, stream>>>(
          Wp + (long)l * DFF * DMODEL, tP, DFF, DMODEL, 0, 0);
    }

    ln_kernel<<<dim3(NTOK), blk, 0, stream>>>(x, ln1g + l * DMODEL, ln1b + l * DMODEL, h);
    // qkv = LN1(x) @ Wqkv + bqkv  (all f16 out; TN=64: 1152 blocks)
    gemm_bt_kernel<64, 64, 1, 0, 0, 0, 1, 0, 0, 0>
        <<<dim3(DQKV / 64, NTOK / 64), blk128, 0, stream>>>(
        (const short*)h, (const short*)tQl, bqkv + (long)l * DQKV,
        nullptr, qkvb, DMODEL, DQKV);

    attn_kernel<<<dim3(S_LEN / 64, 2 * NHEAD), blk, 0, stream>>>(qkvb, ob);

    // x += ob @ Wo + bo  (TN=64: 384 blocks)
    gemm_bt_kernel<64, 64, 1, 0, 1, 0, 0, 0, 0, 0>
        <<<dim3(DMODEL / 64, NTOK / 64), blk128, 0, stream>>>(
        (const short*)ob, (const short*)tOl, bo + (long)l * DMODEL,
        x, nullptr, DMODEL, DMODEL);

    ln_kernel<<<dim3(NTOK), blk, 0, stream>>>(x, ln2g + l * DMODEL, ln2b + l * DMODEL, h);
    // mb = gelu(LN2(x) @ Wfc + bfc) (bf16 out; TN=64: 1536 blocks)
    gemm_bt_kernel<64, 64, 1, 1, 0, 1, 0, 0, 0, 0>
        <<<dim3(DFF / 64, NTOK / 64), blk128, 0, stream>>>(
        (const short*)h, (const short*)tFl, bfc + (long)l * DFF,
        nullptr, mb, DMODEL, DFF);

    // x += mb @ Wp + bp  (TN=64: 384 blocks)
    gemm_bt_kernel<64, 64, 1, 0, 1, 0, 0, 0, 0, 0>
        <<<dim3(DMODEL / 64, NTOK / 64), blk128, 0, stream>>>(
        (const short*)mb, (const short*)tPl, bp + (long)l * DMODEL,
        x, nullptr, DFF, DMODEL);
  }

  ln_kernel<<<dim3(NTOK), blk, 0, stream>>>(x, lnfg, lnfb, h);
  // LM head: TM=128, grid swapped (row fastest) + bijective XCD chunking
  gemm_bt_kernel<128, 128, 0, 0, 0, 0, 0, 1, 1, 1>
      <<<dim3(NTOK / 128, (VOCAB + 127) / 128), blk, 0, stream>>>(
      (const short*)h, (const short*)wteb, nullptr, out, nullptr, DMODEL, VOCAB);
}

// Round 19
// 2212.837 us; speedup vs baseline: 1.0823x; 1.0823x over previous
//
#include <hip/hip_runtime.h>
#include <hip/hip_bf16.h>
#include <hip/hip_fp16.h>

// GPT-2 small forward (B=2,S=1024,L=12,D=768,H=12,V=50257) on gfx950.
// Round 19: FINAL REVERT to round 14's exact source (best measured:
// 2213us, absmax 0.0234). r18's counted-vmcnt T4 graft regressed −168us:
// LDS 16->32KB halved blocks/CU (10->5), killing the TLP that already hid
// the drain stall (regime-gate: T4 pays only in 8-phase role-split
// structures, null-to-negative on 2-phase — m218/m230 confirmed here).
// Session ladder: 5545 (r1) -> 2882 (r2) -> 2793 (r3) -> 2279 (r9) ->
// 2213 (r14, this kernel).

typedef __attribute__((ext_vector_type(8))) short short8;
typedef __attribute__((ext_vector_type(4))) float f32x4;

#define S_LEN  1024
#define NTOK   2048
#define DMODEL 768
#define NHEAD  12
#define HEADD  64
#define NLAYER 12
#define VOCAB  50257
#define DQKV   2304
#define DFF    3072

__device__ __forceinline__ unsigned short f2bf(float f) {
  unsigned u = __float_as_uint(f);
  u += 0x7fffu + ((u >> 16) & 1u);
  return (unsigned short)(u >> 16);
}
__device__ __forceinline__ unsigned short f2h(float f) {
  __half h = __float2half(f);
  return *reinterpret_cast<unsigned short*>(&h);
}

__device__ __forceinline__ f32x4 mfma_bf16(short8 a, short8 b, f32x4 c) {
  asm("v_mfma_f32_16x16x32_bf16 %0, %1, %2, %0" : "+v"(c) : "v"(a), "v"(b));
  return c;
}
__device__ __forceinline__ f32x4 mfma_f16(short8 a, short8 b, f32x4 c) {
  asm("v_mfma_f32_16x16x32_f16 %0, %1, %2, %0" : "+v"(c) : "v"(a), "v"(b));
  return c;
}

// async global->LDS, 16 bytes per lane (dest = wave-uniform base + lane*16)
__device__ __forceinline__ void gll16(const void* g, void* l) {
  __builtin_amdgcn_global_load_lds(
      (const __attribute__((address_space(1))) void*)g,
      (__attribute__((address_space(3))) void*)l, 16, 0, 0);
}

// ---------------- embedding ----------------
__global__ __launch_bounds__(256) void embed_kernel(
    const int* __restrict__ ids, const float* __restrict__ wte,
    const float* __restrict__ wpe, float* __restrict__ x) {
  int i = blockIdx.x * 256 + threadIdx.x;
  int n = i / DMODEL, d = i - n * DMODEL;
  int s = n & (S_LEN - 1);
  x[i] = wte[(long)ids[n] * DMODEL + d] + wpe[(long)s * DMODEL + d];
}

// ---------------- f32 -> bf16 convert (x4) ----------------
__global__ __launch_bounds__(256) void convert_kernel(
    const float* __restrict__ in, unsigned short* __restrict__ out, long n4) {
  long i = (long)blockIdx.x * 256 + threadIdx.x;
  if (i >= n4) return;
  float4 v = ((const float4*)in)[i];
  ushort4 r;
  r.x = f2bf(v.x); r.y = f2bf(v.y); r.z = f2bf(v.z); r.w = f2bf(v.w);
  ((ushort4*)out)[i] = r;
}

// ---------------- transpose f32[R][C] -> bf16[C][R], batched over z ----------------
__global__ __launch_bounds__(256) void transpose_kernel(
    const float* __restrict__ in, unsigned short* __restrict__ out, int R, int C,
    long ldin, long ldout) {
  in  += (long)blockIdx.z * ldin;
  out += (long)blockIdx.z * ldout;
  __shared__ float tile[32][33];
  int tx = threadIdx.x & 31, ty = threadIdx.x >> 5;
  int c0 = blockIdx.x * 32, r0 = blockIdx.y * 32;
#pragma unroll
  for (int i = 0; i < 4; ++i) {
    int r = r0 + ty + i * 8;
    tile[ty + i * 8][tx] = in[(long)r * C + c0 + tx];
  }
  __syncthreads();
#pragma unroll
  for (int i = 0; i < 4; ++i) {
    int orow = c0 + ty + i * 8;
    out[(long)orow * R + r0 + tx] = f2bf(tile[tx][ty + i * 8]);
  }
}

// ---------------- layernorm: f32 in -> bf16 out ----------------
__global__ __launch_bounds__(256) void ln_kernel(
    const float* __restrict__ x, const float* __restrict__ g,
    const float* __restrict__ b, unsigned short* __restrict__ out) {
  __shared__ float sb[4];
  int n = blockIdx.x, t = threadIdx.x;
  const float* xr = x + (long)n * DMODEL;
  float v0 = xr[t], v1 = xr[t + 256], v2 = xr[t + 512];
  float sum = v0 + v1 + v2;
#pragma unroll
  for (int o = 32; o; o >>= 1) sum += __shfl_xor(sum, o);
  if ((t & 63) == 0) sb[t >> 6] = sum;
  __syncthreads();
  sum = sb[0] + sb[1] + sb[2] + sb[3];
  float mean = sum * (1.f / 768.f);
  float d0 = v0 - mean, d1 = v1 - mean, d2 = v2 - mean;
  float vs = d0 * d0 + d1 * d1 + d2 * d2;
#pragma unroll
  for (int o = 32; o; o >>= 1) vs += __shfl_xor(vs, o);
  __syncthreads();
  if ((t & 63) == 0) sb[t >> 6] = vs;
  __syncthreads();
  vs = sb[0] + sb[1] + sb[2] + sb[3];
  float rs = rsqrtf(vs * (1.f / 768.f) + 1e-5f);
  out[(long)n * DMODEL + t]       = f2bf(d0 * rs * g[t] + b[t]);
  out[(long)n * DMODEL + t + 256] = f2bf(d1 * rs * g[t + 256] + b[t + 256]);
  out[(long)n * DMODEL + t + 512] = f2bf(d2 * rs * g[t + 512] + b[t + 512]);
}

// ---------------- MFMA flash attention (all-f16 QKV, r9-verified) ----------------
// qkv: f16 [NTOK][2304]. o: bf16 [NTOK][768].
// grid = (S/64, B*H), block 256 = 4 waves; wave w owns q-rows w*16..w*16+15.
__global__ __launch_bounds__(256) void attn_kernel(
    const unsigned short* __restrict__ qkv, unsigned short* __restrict__ o_out) {
  __shared__ __align__(16) unsigned short Ks[64 * 64];  // K (f16), XOR-swizzled rows
  __shared__ __align__(16) unsigned short Vt[64 * 64];  // [dv][key] f16, swizzled
  __shared__ __align__(16) unsigned short Ps[4][16 * 72];
  int t = threadIdx.x, w = t >> 6, l = t & 63;
  int qtile = blockIdx.x, bh = blockIdx.y;
  int b = bh / NHEAD, h = bh - b * NHEAD;
  long nb = (long)b * S_LEN;
  int g = l >> 4, lr = l & 15;

  int q0 = qtile * 64 + w * 16;
  const unsigned short* qrow = qkv + (nb + q0 + lr) * (long)DQKV + h * HEADD;
  short8 qf0 = *(const short8*)(qrow + g * 8);
  short8 qf1 = *(const short8*)(qrow + 32 + g * 8);

  f32x4 O[4];
  f32x4 zero = {0.f, 0.f, 0.f, 0.f};
#pragma unroll
  for (int jt = 0; jt < 4; ++jt) O[jt] = zero;
  float m[4] = {-INFINITY, -INFINITY, -INFINITY, -INFINITY};
  float ls[4] = {0.f, 0.f, 0.f, 0.f};

  int skey = t >> 2;            // V staging: key row
  int sd0 = (t & 3) * 16;       // V staging: dv0
  int nt = qtile + 1;
  for (int c = 0; c < nt; ++c) {
    int k0 = c * 64;
    __syncthreads();
    // ---- stage K (f16) via global_load_lds, source pre-swizzled ----
    {
      int c0 = t, row = c0 >> 3, j = c0 & 7;
      long goff = (nb + k0 + row) * (long)DQKV + DMODEL + h * HEADD + ((j ^ (row & 7)) * 8);
      gll16(qkv + goff, (char*)Ks + c0 * 16);
      int c1 = t + 256; row = c1 >> 3; j = c1 & 7;
      goff = (nb + k0 + row) * (long)DQKV + DMODEL + h * HEADD + ((j ^ (row & 7)) * 8);
      gll16(qkv + goff, (char*)Ks + c1 * 16);
    }
    // ---- stage V transposed (reg-staged, swizzled 2B writes, f16 passthrough) ----
    {
      const unsigned short* vr =
          qkv + (nb + k0 + skey) * (long)DQKV + 2 * DMODEL + h * HEADD + sd0;
      short8 v0 = *(const short8*)vr;
      short8 v1 = *(const short8*)(vr + 8);
#pragma unroll
      for (int j = 0; j < 8; ++j) {
        int dv = sd0 + j;
        *(unsigned short*)((char*)Vt + dv * 128 + ((skey * 2) ^ ((dv & 7) << 4))) =
            (unsigned short)v0[j];
        dv = sd0 + 8 + j;
        *(unsigned short*)((char*)Vt + dv * 128 + ((skey * 2) ^ ((dv & 7) << 4))) =
            (unsigned short)v1[j];
      }
    }
    __syncthreads();

    // ---- S = Q K^T (f16 inputs, f32 accum) — T5: setprio around MFMA ----
    f32x4 S[4];
    __builtin_amdgcn_s_setprio(1);
#pragma unroll
    for (int kt = 0; kt < 4; ++kt) {
      int krow = kt * 16 + lr;
      int o0 = (g * 16) ^ ((krow & 7) << 4);
      int o1 = (64 + g * 16) ^ ((krow & 7) << 4);
      short8 kf0 = *(const short8*)((char*)Ks + krow * 128 + o0);
      short8 kf1 = *(const short8*)((char*)Ks + krow * 128 + o1);
      S[kt] = mfma_f16(qf0, kf0, zero);
      S[kt] = mfma_f16(qf1, kf1, S[kt]);
    }
    __builtin_amdgcn_s_setprio(0);

    // ---- mask + online softmax (rows lane-local: q = g*4+r) ----
    bool diag = (c == qtile);
    float sv[4][4];
#pragma unroll
    for (int kt = 0; kt < 4; ++kt)
#pragma unroll
      for (int r = 0; r < 4; ++r) {
        float xv = S[kt][r] * 0.125f;
        if (diag) {
          int key = kt * 16 + lr;
          int qq = w * 16 + g * 4 + r;
          if (key > qq) xv = -INFINITY;
        }
        sv[kt][r] = xv;
      }
    float nm[4], al[4];
#pragma unroll
    for (int r = 0; r < 4; ++r) {
      float mx = fmaxf(fmaxf(sv[0][r], sv[1][r]), fmaxf(sv[2][r], sv[3][r]));
#pragma unroll
      for (int o = 8; o; o >>= 1) mx = fmaxf(mx, __shfl_xor(mx, o));
      nm[r] = fmaxf(m[r], mx);
      al[r] = __expf(m[r] - nm[r]);
      m[r] = nm[r];
    }
    float rs[4] = {0.f, 0.f, 0.f, 0.f};
#pragma unroll
    for (int kt = 0; kt < 4; ++kt)
#pragma unroll
      for (int r = 0; r < 4; ++r) {
        float p = __expf(sv[kt][r] - nm[r]);
        rs[r] += p;
        Ps[w][(g * 4 + r) * 72 + kt * 16 + lr] = f2h(p);
      }
#pragma unroll
    for (int r = 0; r < 4; ++r) {
#pragma unroll
      for (int o = 8; o; o >>= 1) rs[r] += __shfl_xor(rs[r], o);
      ls[r] = ls[r] * al[r] + rs[r];
    }
#pragma unroll
    for (int jt = 0; jt < 4; ++jt) {
      f32x4 ov = O[jt];
#pragma unroll
      for (int r = 0; r < 4; ++r) ov[r] *= al[r];
      O[jt] = ov;
    }
    // ---- O += P V (f16) — T5: setprio around MFMA ----
    __builtin_amdgcn_s_setprio(1);
#pragma unroll
    for (int kk = 0; kk < 2; ++kk) {
      short8 pf = *(const short8*)(&Ps[w][lr * 72 + kk * 32 + g * 8]);
#pragma unroll
      for (int jt = 0; jt < 4; ++jt) {
        int dv = jt * 16 + lr;
        short8 vf = *(const short8*)((char*)Vt + dv * 128 +
                                     (((kk * 64 + g * 16)) ^ ((dv & 7) << 4)));
        O[jt] = mfma_f16(pf, vf, O[jt]);
      }
    }
    __builtin_amdgcn_s_setprio(0);
  }

  // ---- epilogue: normalize, stage in Ks, coalesced store (bf16 out) ----
  __syncthreads();
#pragma unroll
  for (int jt = 0; jt < 4; ++jt)
#pragma unroll
    for (int r = 0; r < 4; ++r) {
      int qq = w * 16 + g * 4 + r;
      int dv = jt * 16 + lr;
      *(unsigned short*)((char*)Ks + qq * 128 + ((dv * 2) ^ ((qq & 7) << 4))) =
          f2bf(O[jt][r] / ls[r]);
    }
  __syncthreads();
  {
    int qq = t >> 2, d0 = (t & 3) * 16;
    short8 o0 = *(const short8*)((char*)Ks + qq * 128 + ((d0 * 2) ^ ((qq & 7) << 4)));
    short8 o1 = *(const short8*)((char*)Ks + qq * 128 + (((d0 + 8) * 2) ^ ((qq & 7) << 4)));
    unsigned short* orow = o_out + (nb + qtile * 64 + qq) * (long)DMODEL + h * HEADD + d0;
    *(short8*)orow = o0;
    *(short8*)(orow + 8) = o1;
  }
}

// ---------------- bf16 MFMA GEMM, B^T layout, global_load_lds staging ----------------
// C[M][Nv] = act(A[M][K] * Bt[Nv][K]^T + bias).  K%64==0.
// Two 32-wide K-subtiles per barrier pair.
// TM=128 (TN=128): 4 waves (2x2 of 64x64), 256 thr.
// TM=64: 2 waves, 128 thr; TN=128 (waves split N by 64) or TN=64 (split by 32).
template <int TM, int TN, int HAS_BIAS, int ACT_GELU, int RESID, int OUT_BF16,
          int OUT_F16, int COLG, int GRIDSWAP, int XCDSWZ>
__global__ __launch_bounds__(TM == 128 ? 256 : 128) void gemm_bt_kernel(
    const short* __restrict__ A, const short* __restrict__ Bt,
    const float* __restrict__ bias, float* __restrict__ Cf,
    unsigned short* __restrict__ Cb, int K, int Nv) {
  __shared__ __align__(16) short As[2][TM * 32];
  __shared__ __align__(16) short Bs[2][TN * 32];
  constexpr int NJ = (TN == 64) ? 2 : 4;        // N-frags per wave
  constexpr int WN = (TN == 64) ? 32 : 64;      // wave N-stride
  int t = threadIdx.x;
  int lane = t & 63, wave = t >> 6;
  int wm = (TM == 128) ? (wave >> 1) : 0;
  int wn = (TM == 128) ? (wave & 1) : wave;

  int bx = blockIdx.x, by = blockIdx.y;
  if (XCDSWZ) {
    int gx = gridDim.x;
    int nwg = gx * gridDim.y;
    int wg = by * gx + bx;
    int q8 = nwg >> 3, r8 = nwg & 7;
    int xcd = wg & 7, idx = wg >> 3;
    int nid = (xcd < r8 ? xcd * (q8 + 1) : r8 * (q8 + 1) + (xcd - r8) * q8) + idx;
    bx = nid % gx;
    by = nid / gx;
  }
  int row0 = (GRIDSWAP ? bx : by) * TM;
  int col0 = (GRIDSWAP ? by : bx) * TN;
  int lr = lane & 15, lk = (lane >> 4) * 8;

  f32x4 acc[4][NJ];
  f32x4 zero = {0.f, 0.f, 0.f, 0.f};
#pragma unroll
  for (int i = 0; i < 4; ++i)
#pragma unroll
    for (int j = 0; j < NJ; ++j) acc[i][j] = zero;

  int rr = t >> 2, k8 = (t & 3) * 8;

  if (TM == 128) {
    int ar0 = row0 + rr, ar1 = ar0 + 64;
    int br0 = col0 + rr, br1 = br0 + 64;
    if (COLG) { br0 = min(br0, Nv - 1); br1 = min(br1, Nv - 1); }
    const short* Ap0 = A + (long)ar0 * K + k8;
    const short* Ap1 = A + (long)ar1 * K + k8;
    const short* Bp0 = Bt + (long)br0 * K + k8;
    const short* Bp1 = Bt + (long)br1 * K + k8;
    for (int kt = 0; kt < K; kt += 64) {
      __syncthreads();
#pragma unroll
      for (int s = 0; s < 2; ++s) {
        int ko = kt + s * 32;
        gll16(Ap0 + ko, (char*)As[s] + t * 16);
        gll16(Ap1 + ko, (char*)As[s] + 4096 + t * 16);
        gll16(Bp0 + ko, (char*)Bs[s] + t * 16);
        gll16(Bp1 + ko, (char*)Bs[s] + 4096 + t * 16);
      }
      __syncthreads();
#pragma unroll
      for (int s = 0; s < 2; ++s) {
        short8 af[4], bfr[4];
#pragma unroll
        for (int i = 0; i < 4; ++i) {
          af[i]  = *(const short8*)(As[s] + (wm * 64 + i * 16 + lr) * 32 + lk);
          bfr[i] = *(const short8*)(Bs[s] + (wn * 64 + i * 16 + lr) * 32 + lk);
        }
#pragma unroll
        for (int i = 0; i < 4; ++i)
#pragma unroll
          for (int j = 0; j < 4; ++j)
            acc[i][j] = mfma_bf16(af[i], bfr[j], acc[i][j]);
      }
    }
  } else if (TN == 128) {
    // TM == 64, TN == 128, 128 threads
    const short* Ap = A + (long)(row0 + rr) * K + k8;
    const short* Bp = Bt + (long)(col0 + rr) * K + k8;
    for (int kt = 0; kt < K; kt += 64) {
      __syncthreads();
#pragma unroll
      for (int s = 0; s < 2; ++s) {
        int ko = kt + s * 32;
        gll16(Ap + ko, (char*)As[s] + t * 16);
        gll16(Ap + (long)32 * K + ko, (char*)As[s] + 2048 + t * 16);
        gll16(Bp + ko, (char*)Bs[s] + t * 16);
        gll16(Bp + (long)32 * K + ko, (char*)Bs[s] + 2048 + t * 16);
        gll16(Bp + (long)64 * K + ko, (char*)Bs[s] + 4096 + t * 16);
        gll16(Bp + (long)96 * K + ko, (char*)Bs[s] + 6144 + t * 16);
      }
      __syncthreads();
#pragma unroll
      for (int s = 0; s < 2; ++s) {
        short8 af[4], bfr[4];
#pragma unroll
        for (int i = 0; i < 4; ++i) {
          af[i]  = *(const short8*)(As[s] + (i * 16 + lr) * 32 + lk);
          bfr[i] = *(const short8*)(Bs[s] + (wn * 64 + i * 16 + lr) * 32 + lk);
        }
#pragma unroll
        for (int i = 0; i < 4; ++i)
#pragma unroll
          for (int j = 0; j < 4; ++j)
            acc[i][j] = mfma_bf16(af[i], bfr[j], acc[i][j]);
      }
    }
  } else {
    // TM == 64, TN == 64, 128 threads (2 waves split N by 32)
    const short* Ap = A + (long)(row0 + rr) * K + k8;
    const short* Bp = Bt + (long)(col0 + rr) * K + k8;
    for (int kt = 0; kt < K; kt += 64) {
      __syncthreads();
#pragma unroll
      for (int s = 0; s < 2; ++s) {
        int ko = kt + s * 32;
        gll16(Ap + ko, (char*)As[s] + t * 16);
        gll16(Ap + (long)32 * K + ko, (char*)As[s] + 2048 + t * 16);
        gll16(Bp + ko, (char*)Bs[s] + t * 16);
        gll16(Bp + (long)32 * K + ko, (char*)Bs[s] + 2048 + t * 16);
      }
      __syncthreads();
#pragma unroll
      for (int s = 0; s < 2; ++s) {
        short8 af[4], bfr[2];
#pragma unroll
        for (int i = 0; i < 4; ++i)
          af[i] = *(const short8*)(As[s] + (i * 16 + lr) * 32 + lk);
#pragma unroll
        for (int j = 0; j < 2; ++j)
          bfr[j] = *(const short8*)(Bs[s] + (wn * 32 + j * 16 + lr) * 32 + lk);
#pragma unroll
        for (int i = 0; i < 4; ++i)
#pragma unroll
          for (int j = 0; j < 2; ++j)
            acc[i][j] = mfma_bf16(af[i], bfr[j], acc[i][j]);
      }
    }
  }

  int orow = row0 + wm * 64 + (lane >> 4) * 4;
  int ocol = col0 + wn * WN + lr;
#pragma unroll
  for (int i = 0; i < 4; ++i) {
#pragma unroll
    for (int j = 0; j < NJ; ++j) {
      int col = ocol + j * 16;
      if (COLG && col >= Nv) continue;
      float bv = 0.f;
      if (HAS_BIAS) bv = bias[col];
#pragma unroll
      for (int r = 0; r < 4; ++r) {
        float xv = acc[i][j][r] + bv;
        if (ACT_GELU) xv = 0.5f * xv * (1.f + erff(xv * 0.70710678118654752f));
        long idx = (long)(orow + i * 16 + r) * Nv + col;
        if (RESID) {
          Cf[idx] += xv;
        } else if (OUT_F16) {
          Cb[idx] = f2h(xv);
        } else if (OUT_BF16) {
          Cb[idx] = f2bf(xv);
        } else {
          Cf[idx] = xv;
        }
      }
    }
  }
}

extern "C" void kernel_launch(void* const* d_in, const int* in_sizes, int n_in,
                              void* d_out, int out_size, void* d_ws, size_t ws_size,
                              hipStream_t stream) {
  const int*   ids  = (const int*)d_in[0];
  const float* wte  = (const float*)d_in[1];
  const float* wpe  = (const float*)d_in[2];
  const float* ln1g = (const float*)d_in[3];
  const float* ln1b = (const float*)d_in[4];
  const float* Wqkv = (const float*)d_in[5];
  const float* bqkv = (const float*)d_in[6];
  const float* Wo   = (const float*)d_in[7];
  const float* bo   = (const float*)d_in[8];
  const float* ln2g = (const float*)d_in[9];
  const float* ln2b = (const float*)d_in[10];
  const float* Wfc  = (const float*)d_in[11];
  const float* bfc  = (const float*)d_in[12];
  const float* Wp   = (const float*)d_in[13];
  const float* bp   = (const float*)d_in[14];
  const float* lnfg = (const float*)d_in[15];
  const float* lnfb = (const float*)d_in[16];
  float* out = (float*)d_out;

  size_t off = 0;
  auto carve = [&](size_t bytes) {
    void* p = (char*)d_ws + off;
    off += (bytes + 255) & ~(size_t)255;
    return p;
  };
  float* x = (float*)carve((size_t)NTOK * DMODEL * 4);
  unsigned short* qkvb = (unsigned short*)carve((size_t)NTOK * DQKV * 2);
  unsigned short* h    = (unsigned short*)carve((size_t)NTOK * DMODEL * 2);
  unsigned short* ob   = (unsigned short*)carve((size_t)NTOK * DMODEL * 2);
  unsigned short* mb   = (unsigned short*)carve((size_t)NTOK * DFF * 2);
  unsigned short* wteb = (unsigned short*)carve((size_t)VOCAB * DMODEL * 2);

  const size_t szQ = (size_t)DMODEL * DQKV * 2, szO = (size_t)DMODEL * DMODEL * 2;
  const size_t szF = (size_t)DMODEL * DFF * 2,  szP = (size_t)DFF * DMODEL * 2;
  size_t fixed_end = off;
  size_t full_need = fixed_end + NLAYER * (szQ + szO + szF + szP) + 4 * 256;
  bool full = ws_size >= full_need;

  unsigned short *tQ, *tO, *tF, *tP;
  if (full) {
    tQ = (unsigned short*)carve(NLAYER * szQ);
    tO = (unsigned short*)carve(NLAYER * szO);
    tF = (unsigned short*)carve(NLAYER * szF);
    tP = (unsigned short*)carve(NLAYER * szP);
  } else {
    tQ = (unsigned short*)carve(szQ);
    tO = (unsigned short*)carve(szO);
    tF = (unsigned short*)carve(szF);
    tP = (unsigned short*)carve(szP);
  }
  if (off > ws_size) return;

  dim3 blk(256), blk128(128);
  long n4 = (long)VOCAB * DMODEL / 4;
  convert_kernel<<<dim3((unsigned)((n4 + 255) / 256)), blk, 0, stream>>>(wte, wteb, n4);
  embed_kernel<<<dim3(NTOK * DMODEL / 256), blk, 0, stream>>>(ids, wte, wpe, x);

  if (full) {
    transpose_kernel<<<dim3(DQKV / 32, DMODEL / 32, NLAYER), blk, 0, stream>>>(
        Wqkv, tQ, DMODEL, DQKV, (long)DMODEL * DQKV, (long)DMODEL * DQKV);
    transpose_kernel<<<dim3(DMODEL / 32, DMODEL / 32, NLAYER), blk, 0, stream>>>(
        Wo, tO, DMODEL, DMODEL, (long)DMODEL * DMODEL, (long)DMODEL * DMODEL);
    transpose_kernel<<<dim3(DFF / 32, DMODEL / 32, NLAYER), blk, 0, stream>>>(
        Wfc, tF, DMODEL, DFF, (long)DMODEL * DFF, (long)DMODEL * DFF);
    transpose_kernel<<<dim3(DMODEL / 32, DFF / 32, NLAYER), blk, 0, stream>>>(
        Wp, tP, DFF, DMODEL, (long)DFF * DMODEL, (long)DFF * DMODEL);
  }

  for (int l = 0; l < NLAYER; ++l) {
    const unsigned short* tQl = tQ + (full ? (size_t)l * DMODEL * DQKV : 0);
    const unsigned short* tOl = tO + (full ? (size_t)l * DMODEL * DMODEL : 0);
    const unsigned short* tFl = tF + (full ? (size_t)l * DMODEL * DFF : 0);
    const unsigned short* tPl = tP + (full ? (size_t)l * DFF * DMODEL : 0);
    if (!full) {
      transpose_kernel<<<dim3(DQKV / 32, DMODEL / 32), blk, 0, stream>>>(
          Wqkv + (long)l * DMODEL * DQKV, tQ, DMODEL, DQKV, 0, 0);
      transpose_kernel<<<dim3(DMODEL / 32, DMODEL / 32), blk, 0, stream>>>(
          Wo + (long)l * DMODEL * DMODEL, tO, DMODEL, DMODEL, 0, 0);
      transpose_kernel<<<dim3(DFF / 32, DMODEL / 32), blk, 0, stream>>>(
          Wfc + (long)l * DMODEL * DFF, tF, DMODEL, DFF, 0, 0);
      transpose_kernel<<<dim3(DMODEL / 32, DFF / 32), blk, 0, stream>>>(
          Wp + (long)l * DFF * DMODEL, tP, DFF, DMODEL, 0, 0);
    }

    ln_kernel<<<dim3(NTOK), blk, 0, stream>>>(x, ln1g + l * DMODEL, ln1b + l * DMODEL, h);
    // qkv = LN1(x) @ Wqkv + bqkv  (all f16 out)
    gemm_bt_kernel<64, 128, 1, 0, 0, 0, 1, 0, 0, 0>
        <<<dim3(DQKV / 128, NTOK / 64), blk128, 0, stream>>>(
        (const short*)h, (const short*)tQl, bqkv + (long)l * DQKV,
        nullptr, qkvb, DMODEL, DQKV);

    attn_kernel<<<dim3(S_LEN / 64, 2 * NHEAD), blk, 0, stream>>>(qkvb, ob);

    // x += ob @ Wo + bo  (TN=64: 384 blocks)
    gemm_bt_kernel<64, 64, 1, 0, 1, 0, 0, 0, 0, 0>
        <<<dim3(DMODEL / 64, NTOK / 64), blk128, 0, stream>>>(
        (const short*)ob, (const short*)tOl, bo + (long)l * DMODEL,
        x, nullptr, DMODEL, DMODEL);

    ln_kernel<<<dim3(NTOK), blk, 0, stream>>>(x, ln2g + l * DMODEL, ln2b + l * DMODEL, h);
    // mb = gelu(LN2(x) @ Wfc + bfc) (bf16 out)
    gemm_bt_kernel<64, 128, 1, 1, 0, 1, 0, 0, 0, 0>
        <<<dim3(DFF / 128, NTOK / 64), blk128, 0, stream>>>(
        (const short*)h, (const short*)tFl, bfc + (long)l * DFF,
        nullptr, mb, DMODEL, DFF);

    // x += mb @ Wp + bp  (TN=64: 384 blocks)
    gemm_bt_kernel<64, 64, 1, 0, 1, 0, 0, 0, 0, 0>
        <<<dim3(DMODEL / 64, NTOK / 64), blk128, 0, stream>>>(
        (const short*)mb, (const short*)tPl, bp + (long)l * DMODEL,
        x, nullptr, DFF, DMODEL);
  }

  ln_kernel<<<dim3(NTOK), blk, 0, stream>>>(x, lnfg, lnfb, h);
  // LM head: TM=128, grid swapped (row fastest) + bijective XCD chunking
  gemm_bt_kernel<128, 128, 0, 0, 0, 0, 0, 1, 1, 1>
      <<<dim3(NTOK / 128, (VOCAB + 127) / 128), blk, 0, stream>>>(
      (const short*)h, (const short*)wteb, nullptr, out, nullptr, DMODEL, VOCAB);
}